// Round 3
// baseline (172.617 us; speedup 1.0000x reference)
//
#include <hip/hip_runtime.h>
#include <stdint.h>

#define Bb 8
#define Dd 256
#define Ll 4096
#define Kk 4096
#define Nn (Bb * Ll)          // 32768 rows
#define OUT0 (Bb * Dd * Ll)   // 8388608

typedef int    int4v   __attribute__((ext_vector_type(4)));
typedef int    int8v   __attribute__((ext_vector_type(8)));
typedef float  floatx4 __attribute__((ext_vector_type(4)));

#define SCALE1 0x7F7F7F7F     // E8M0 exp=127 -> x1.0 for every 32-elem block

union V8 { int8v v; int4v h[2]; };

__device__ __forceinline__ void async_load16(const void* g, void* l) {
    __builtin_amdgcn_global_load_lds((const __attribute__((address_space(1))) void*)g,
                                     (__attribute__((address_space(3))) void*)l, 16, 0, 0);
}

// ---------------------------------------------------------------- kernel 1
// normalize codebook rows, scale x16, cast fp8 e4m3 (block 0 zeroes
// counts + lossacc + done). wn[k][d] = fp8(16 * w[k][d] / max(||w_k||,eps))
__global__ void k_prep(const float* __restrict__ w, unsigned char* __restrict__ wn,
                       int* __restrict__ counts) {
    int blk = blockIdx.x, tid = threadIdx.x;
    if (blk == 0)
        for (int i = tid; i < Kk + 2; i += 256) counts[i] = 0;
    int row  = blk * 4 + (tid >> 6);
    int lane = tid & 63;
    float4 v = ((const float4*)(w + (size_t)row * Dd))[lane];
    float ss = v.x*v.x + v.y*v.y + v.z*v.z + v.w*v.w;
#pragma unroll
    for (int m = 1; m < 64; m <<= 1) ss += __shfl_xor(ss, m, 64);
    float s = 16.0f / fmaxf(sqrtf(ss), 1e-12f);
    int p = __builtin_amdgcn_cvt_pk_fp8_f32(v.x * s, v.y * s, 0, false);
    p     = __builtin_amdgcn_cvt_pk_fp8_f32(v.z * s, v.w * s, p, true);
    ((int*)(wn + (size_t)row * Dd))[lane] = p;
}

// ---------------------------------------------------------------- kernel 2
// fused transpose + fp8 cast + full-col argmax GEMM + gather/loss epilogue.
// RESIDENCY FIX (rounds 1-2 post-mortem): 1 block/CU left both pipes idle
// >60% (MfmaUtil 16%, VALUBusy 17%, HBM 13%) — latency-bound lockstep.
// Now 512 blocks x 256 thr, 64 rows x 4096 cols each; LDS 48KB ->
// 2 blocks/CU co-resident whose phases mutually hide stalls (m97 recipe).
// Simple loop: issue next 64-col B tile DMA, ds_read, MFMA, keypack, one
// __syncthreads per cb. Reduction scratch overlays the dead As region.
// XCD swizzle: bm=(bid&7)*64+(bid>>3) -> each XCD owns one batch b, so
// x-slab + epilogue re-read live in its own L2; bijective (512%8==0).
__global__ __launch_bounds__(256, 3) void k_gemm_fused(
        const float* __restrict__ x, const unsigned char* __restrict__ Wn,
        const float* __restrict__ w, float* __restrict__ out,
        int* __restrict__ counts) {
    __shared__ __align__(16) unsigned char As[64 * 256];      // 16 KB
    __shared__ __align__(16) unsigned char Bs[2][64 * 256];   // 32 KB
    // overlays on As (dead after af-load; af lives in regs through the loop)
    unsigned int (*red)[4] = (unsigned int (*)[4])(void*)As;  // 1 KB
    int*   kidx  = (int*)(void*)(As + 1024);                  // 256 B
    float* wsum  = (float*)(void*)(As + 1280);                // 16 B
    int*   lastp = (int*)(void*)(As + 1296);

    float* lossacc = (float*)(counts + Kk);
    int*   done    = counts + Kk + 1;

    int bid = blockIdx.x;
    int bm = ((bid & 7) << 6) | (bid >> 3);   // XCD j -> orig 64j..64j+63
    int tid = threadIdx.x, lane = tid & 63, wv = tid >> 6;
    int l15 = lane & 15, l4 = lane >> 4;

    // B DMA maps: tile = 64 cols x 256 B = 1024 chunks; 4 per thread.
    // LDS slot q holds global 16B chunk (col=q>>4, c=(q&15)^(col&15))
    int goff[4], loff[4];
#pragma unroll
    for (int j = 0; j < 4; ++j) {
        int q = j * 256 + tid;
        int col = q >> 4, p = q & 15;
        goff[j] = col * 256 + ((p ^ (col & 15)) << 4);
        loff[j] = q * 16;
    }

    // prologue DMA: col-tile 0 -> Bs[0] (overlaps transpose; sync drains)
#pragma unroll
    for (int j = 0; j < 4; ++j)
        async_load16(Wn + goff[j], (unsigned char*)Bs[0] + loff[j]);

    // ---- fused transpose: x slab [256 d][64 l] f32 -> As[l][d] fp8 (swz)
    int b = bm >> 6, l0 = (bm & 63) * 64;
    const float* xs = x + (size_t)b * Dd * Ll + l0;
    int lg = tid & 15, dgr = tid >> 4;    // 16 l-groups x 16 d-groups
#pragma unroll
    for (int i = 0; i < 4; ++i) {
        int d0 = dgr * 4 + i * 64;
        const float* s0 = xs + (size_t)d0 * Ll + lg * 4;
        float4 f0 = *(const float4*)(s0);
        float4 f1 = *(const float4*)(s0 + Ll);
        float4 f2 = *(const float4*)(s0 + 2 * (size_t)Ll);
        float4 f3 = *(const float4*)(s0 + 3 * (size_t)Ll);
#pragma unroll
        for (int jl = 0; jl < 4; ++jl) {
            float a0 = ((const float*)&f0)[jl], a1 = ((const float*)&f1)[jl];
            float a2 = ((const float*)&f2)[jl], a3 = ((const float*)&f3)[jl];
            int pk = __builtin_amdgcn_cvt_pk_fp8_f32(a0, a1, 0, false);
            pk     = __builtin_amdgcn_cvt_pk_fp8_f32(a2, a3, pk, true);
            int l = lg * 4 + jl;
            *(int*)(As + l * 256 + (((d0 >> 4) ^ (l & 15)) << 4) + (d0 & 15)) = pk;
        }
    }
    __syncthreads();   // As complete + Bs[0] DMA drained

    // ---- A fragments (64 VGPRs): row = fm*16+l15, k = ks*128+l4*32
    int8v af[4][2];
#pragma unroll
    for (int fm = 0; fm < 4; ++fm)
#pragma unroll
        for (int ks = 0; ks < 2; ++ks) {
            int l = fm * 16 + l15;
            int ch = ks * 8 + l4 * 2;
            V8 u;
            u.h[0] = *(const int4v*)(As + l * 256 + ((ch ^ l15) << 4));
            u.h[1] = *(const int4v*)(As + l * 256 + (((ch + 1) ^ l15) << 4));
            af[fm][ks] = u.v;
        }

    unsigned int rk[4][4];
#pragma unroll
    for (int fm = 0; fm < 4; ++fm)
#pragma unroll
        for (int r = 0; r < 4; ++r) rk[fm][r] = 0u;

    // ---- main loop: 64 tiles of 64 cols; wave wv owns cols wv*16..+15
    for (int cb = 0; cb < 64; ++cb) {
        if (cb < 63) {           // prefetch next tile into other buffer
            const unsigned char* g = Wn + (size_t)(cb + 1) * (64 * 256);
            unsigned char* lb = (unsigned char*)Bs[(cb + 1) & 1];
#pragma unroll
            for (int j = 0; j < 4; ++j)
                async_load16(g + goff[j], lb + loff[j]);
        }
        const unsigned char* bb = (const unsigned char*)Bs[cb & 1];
        int8v bf[2];
#pragma unroll
        for (int ks = 0; ks < 2; ++ks) {
            int col = wv * 16 + l15;          // 0..63
            int ch = ks * 8 + l4 * 2;
            V8 u;
            u.h[0] = *(const int4v*)(bb + col * 256 + ((ch ^ l15) << 4));
            u.h[1] = *(const int4v*)(bb + col * 256 + (((ch + 1) ^ l15) << 4));
            bf[ks] = u.v;
        }
        __builtin_amdgcn_s_setprio(1);
        floatx4 acc[4];
#pragma unroll
        for (int fm = 0; fm < 4; ++fm) {
            floatx4 a = (floatx4)512.0f;      // bias -> positive, int-ordered
            a = __builtin_amdgcn_mfma_scale_f32_16x16x128_f8f6f4(
                    af[fm][0], bf[0], a, 0, 0, 0, SCALE1, 0, SCALE1);
            a = __builtin_amdgcn_mfma_scale_f32_16x16x128_f8f6f4(
                    af[fm][1], bf[1], a, 0, 0, 0, SCALE1, 0, SCALE1);
            acc[fm] = a;
        }
        __builtin_amdgcn_s_setprio(0);
        unsigned int i0 = (unsigned)(cb * 64 + wv * 16 + l15);
#pragma unroll
        for (int fm = 0; fm < 4; ++fm)
#pragma unroll
            for (int r = 0; r < 4; ++r) {
                unsigned int k0 = (__float_as_uint(acc[fm][r]) & 0xFFFFF000u) | i0;
                rk[fm][r] = rk[fm][r] > k0 ? rk[fm][r] : k0;
            }
        __syncthreads();         // guards buffer reuse + drains prefetch DMA
    }

    // epilogue: key-max across 16 col-lanes, then across 4 wave-strips
#pragma unroll
    for (int fm = 0; fm < 4; ++fm)
#pragma unroll
        for (int r = 0; r < 4; ++r) {
            unsigned int kx = rk[fm][r];
#pragma unroll
            for (int md = 1; md <= 8; md <<= 1) {
                unsigned int o = (unsigned int)__shfl_xor((int)kx, md, 64);
                kx = kx > o ? kx : o;
            }
            if (l15 == 0) red[fm * 16 + l4 * 4 + r][wv] = kx;
        }
    __syncthreads();
    if (tid < 64) {
        unsigned int k0 = red[tid][0], k1 = red[tid][1];
        unsigned int k2 = red[tid][2], k3 = red[tid][3];
        unsigned int kx = k0 > k1 ? k0 : k1;
        kx = kx > k2 ? kx : k2;
        kx = kx > k3 ? kx : k3;
        int ix = (int)(kx & 0xFFFu);
        kidx[tid] = ix;
        atomicAdd(&counts[ix], 1);
    }
    __syncthreads();   // kidx visible to all

    // ---- fused gather + out-write + loss, registers only (no LDS stage).
    // Thread (lg,dgr): l = lg*4..+3, d = dgr*4+i*64+dd. x re-read = same
    // float4s as the transpose (own-XCD L2-warm via batch swizzle); w rows
    // read in contiguous 256B per 16-thread dgr-group (w 4MB, L2/L3).
    float ls = 0.f;
    {
        float* os = out + (size_t)b * Dd * Ll + l0;
        int r0 = lg * 4;
#pragma unroll
        for (int i = 0; i < 4; ++i) {
            int d0 = dgr * 4 + i * 64;
            float4 xv[4];
#pragma unroll
            for (int dd = 0; dd < 4; ++dd)
                xv[dd] = *(const float4*)(xs + (size_t)(d0 + dd) * Ll + lg * 4);
            float4 q4[4];
#pragma unroll
            for (int jl = 0; jl < 4; ++jl)
                q4[jl] = *(const float4*)(w + (size_t)kidx[r0 + jl] * Dd + d0);
#pragma unroll
            for (int dd = 0; dd < 4; ++dd) {
                float4 qq;
                qq.x = ((const float*)&q4[0])[dd];
                qq.y = ((const float*)&q4[1])[dd];
                qq.z = ((const float*)&q4[2])[dd];
                qq.w = ((const float*)&q4[3])[dd];
                float e0 = qq.x - xv[dd].x, e1 = qq.y - xv[dd].y;
                float e2 = qq.z - xv[dd].z, e3 = qq.w - xv[dd].w;
                ls += e0*e0 + e1*e1 + e2*e2 + e3*e3;
                *(float4*)(os + (size_t)(d0 + dd) * Ll + lg * 4) = qq;
            }
        }
    }

#pragma unroll
    for (int m = 1; m < 64; m <<= 1) ls += __shfl_xor(ls, m, 64);
    if (lane == 0) wsum[wv] = ls;
    __syncthreads();
    if (tid == 0) {
        atomicAdd(lossacc, wsum[0] + wsum[1] + wsum[2] + wsum[3]);
        __threadfence();
        *lastp = (atomicAdd(done, 1) == 511);
    }
    __syncthreads();
    if (*lastp) {                 // all blocks' counts/loss atomics visible
        __threadfence();
        float s = 0.f;
        for (int i = tid; i < Kk; i += 256) {
            float p = (float)counts[i] * (1.0f / Nn);
            s += p * logf(p + 1e-10f);
        }
#pragma unroll
        for (int m = 1; m < 64; m <<= 1) s += __shfl_xor(s, m, 64);
        if (lane == 0) wsum[wv] = s;
        __syncthreads();
        if (tid == 0) {
            out[OUT0]     = lossacc[0] * 1.25f / (float)OUT0;  // q + 0.25*e latent
            out[OUT0 + 1] = expf(-(wsum[0] + wsum[1] + wsum[2] + wsum[3]));
        }
    }
}

// ---------------------------------------------------------------- launch
extern "C" void kernel_launch(void* const* d_in, const int* in_sizes, int n_in,
                              void* d_out, int out_size, void* d_ws, size_t ws_size,
                              hipStream_t stream) {
    const float* x = (const float*)d_in[0];   // [B, D, L]
    const float* w = (const float*)d_in[1];   // [K, D]
    float* out = (float*)d_out;
    char* ws = (char*)d_ws;

    unsigned char* wn     = (unsigned char*)ws;            // 1 MB fp8
    int*           counts = (int*)(ws + (1u << 20));       // 16 KB + 8 B

    k_prep      <<<1024, 256, 0, stream>>>(w, wn, counts);
    k_gemm_fused<<<512,  256, 0, stream>>>(x, wn, w, out, counts);
}